// Round 3
// baseline (1363.373 us; speedup 1.0000x reference)
//
#include <hip/hip_runtime.h>
#include <cstdint>

namespace {
constexpr int kN = 50000;          // nodes
constexpr int kE = 200000;         // directed edges (pre self-loop)
constexpr int kE2 = kE + kN;       // with self loops
constexpr int kG = 256;            // graphs
constexpr float kNegSlope = 0.2f;
}

using half8   = __attribute__((ext_vector_type(8))) _Float16;
using half4   = __attribute__((ext_vector_type(4))) _Float16;
using floatx4 = __attribute__((ext_vector_type(4))) float;

__device__ __forceinline__ void gld_lds16(const void* g, void* l) {
  __builtin_amdgcn_global_load_lds(
      (const __attribute__((address_space(1))) unsigned int*)g,
      (__attribute__((address_space(3))) unsigned int*)l, 16, 0, 0);
}

// ---------------- f16x3 MFMA GEMM + fused attention dots --------------
// C[M,N] = A[M,K] @ B[K,N]; A row-major hi/lo f16; B pre-transposed [N,K]
// hi/lo f16. 128x128 tile, BK=32, 256 threads = 4 waves (64x64 each).
// Epilogue also accumulates asrc[n,h] += sum_c h[n,c]*a_src[c] via 16-lane
// shuffle reduce + atomicAdd (each wave's 64-col window is within 1 head).
__global__ __launch_bounds__(256) void gemm_f16x3(
    const _Float16* __restrict__ Ah, const _Float16* __restrict__ Al,
    const _Float16* __restrict__ Bh, const _Float16* __restrict__ Bl,
    float* __restrict__ C, const float* __restrict__ a_srcf,
    const float* __restrict__ a_dstf, float* __restrict__ asrc,
    float* __restrict__ adst, int M, int N, int K, int NH) {
  __shared__ alignas(16) char smem[32768];
  char* sAh = smem;
  char* sAl = smem + 8192;
  char* sBh = smem + 16384;
  char* sBl = smem + 24576;
  const int t = threadIdx.x;
  const int w = t >> 6;
  const int l = t & 63;
  const int bm = blockIdx.x * 128;
  const int bn = blockIdx.y * 128;
  const int wm = (w & 1) * 64;
  const int wn = (w >> 1) * 64;
  const int quad = l >> 4;
  const int lrow = l & 15;

  floatx4 acc[4][4];
#pragma unroll
  for (int mi = 0; mi < 4; ++mi)
#pragma unroll
    for (int ni = 0; ni < 4; ++ni) acc[mi][ni] = (floatx4){0.f, 0.f, 0.f, 0.f};

  for (int k0 = 0; k0 < K; k0 += 32) {
#pragma unroll
    for (int j = 0; j < 2; ++j) {
      const int s = w * 128 + j * 64 + l;          // slot id 0..511
      const int row = ((s >> 6) << 4) + (s & 15);  // 0..127
      const int q = (s >> 4) & 3;
      int ga = bm + row;
      ga = (ga < M) ? ga : (M - 1);                // clamp: keep lanes active
      const size_t aofs = (size_t)ga * K + k0 + q * 8;
      const size_t bofs = (size_t)(bn + row) * K + k0 + q * 8;
      gld_lds16(Ah + aofs, sAh + s * 16);
      gld_lds16(Al + aofs, sAl + s * 16);
      gld_lds16(Bh + bofs, sBh + s * 16);
      gld_lds16(Bl + bofs, sBl + s * 16);
    }
    __syncthreads();
    half8 fah[4], fal[4], fbh[4], fbl[4];
#pragma unroll
    for (int mi = 0; mi < 4; ++mi) {
      const int g = (wm >> 4) + mi;
      fah[mi] = *(const half8*)(sAh + g * 1024 + l * 16);
      fal[mi] = *(const half8*)(sAl + g * 1024 + l * 16);
    }
#pragma unroll
    for (int ni = 0; ni < 4; ++ni) {
      const int g = (wn >> 4) + ni;
      fbh[ni] = *(const half8*)(sBh + g * 1024 + l * 16);
      fbl[ni] = *(const half8*)(sBl + g * 1024 + l * 16);
    }
#pragma unroll
    for (int mi = 0; mi < 4; ++mi)
#pragma unroll
      for (int ni = 0; ni < 4; ++ni) {
        acc[mi][ni] = __builtin_amdgcn_mfma_f32_16x16x32_f16(fal[mi], fbh[ni],
                                                             acc[mi][ni], 0, 0, 0);
        acc[mi][ni] = __builtin_amdgcn_mfma_f32_16x16x32_f16(fah[mi], fbl[ni],
                                                             acc[mi][ni], 0, 0, 0);
        acc[mi][ni] = __builtin_amdgcn_mfma_f32_16x16x32_f16(fah[mi], fbh[ni],
                                                             acc[mi][ni], 0, 0, 0);
      }
    __syncthreads();
  }
  // epilogue: C/D layout col=lane&15, row=quad*4+reg
  const int colbase = bn + wn;
  const int head = colbase >> 7;   // 64-col window lies within one head
  float asv[4], adv[4];
#pragma unroll
  for (int ni = 0; ni < 4; ++ni) {
    asv[ni] = a_srcf[colbase + ni * 16 + lrow];
    adv[ni] = a_dstf[colbase + ni * 16 + lrow];
  }
#pragma unroll
  for (int mi = 0; mi < 4; ++mi) {
    const int rbase = bm + wm + mi * 16 + quad * 4;
#pragma unroll
    for (int r = 0; r < 4; ++r) {
      const int grow = rbase + r;
      float s1 = 0.f, s2 = 0.f;
#pragma unroll
      for (int ni = 0; ni < 4; ++ni) {
        const float v = acc[mi][ni][r];
        s1 = fmaf(v, asv[ni], s1);
        s2 = fmaf(v, adv[ni], s2);
      }
#pragma unroll
      for (int off = 1; off < 16; off <<= 1) {
        s1 += __shfl_xor(s1, off);
        s2 += __shfl_xor(s2, off);
      }
      if (grow < M) {
        if (lrow == 0) {
          atomicAdd(&asrc[grow * NH + head], s1);
          atomicAdd(&adst[grow * NH + head], s2);
        }
#pragma unroll
        for (int ni = 0; ni < 4; ++ni) {
          C[(size_t)grow * N + colbase + ni * 16 + lrow] = acc[mi][ni][r];
        }
      }
    }
  }
}

// ---------------- weight transpose + f16 split: W[K,N] -> Wt[N,K] -----
__global__ void wt_split(const float* __restrict__ W, _Float16* __restrict__ Th,
                         _Float16* __restrict__ Tl, int K, int N) {
  const int idx = blockIdx.x * blockDim.x + threadIdx.x;
  if (idx >= K * N) return;
  const int k = idx / N;
  const int n = idx - k * N;
  const float v = W[idx];
  const _Float16 h = (_Float16)v;
  Th[n * K + k] = h;
  Tl[n * K + k] = (_Float16)(v - (float)h);
}

// ---------------- row-major fp32 -> f16 hi/lo split -------------------
__global__ void split16(const float* __restrict__ X, _Float16* __restrict__ Xh,
                        _Float16* __restrict__ Xl, int total) {
  const int idx = blockIdx.x * blockDim.x + threadIdx.x;
  if (idx >= total) return;
  const float v = X[idx];
  const _Float16 h = (_Float16)v;
  Xh[idx] = h;
  Xl[idx] = (_Float16)(v - (float)h);
}

__global__ void zero_f2(float* __restrict__ a, float* __restrict__ b, int n) {
  const int i = blockIdx.x * blockDim.x + threadIdx.x;
  if (i < n) {
    a[i] = 0.f;
    b[i] = 0.f;
  }
}

// ---------------- CSR (by dst) build ----------------------------------
__global__ void zero_int(int* p) {
  if (blockIdx.x == 0 && threadIdx.x == 0) *p = 0;
}
__global__ void init_counts(int* cnt, int n) {
  const int i = blockIdx.x * blockDim.x + threadIdx.x;
  if (i < n) cnt[i] = 1;  // the self loop
}
__global__ void count_edges(const int* __restrict__ dst, int* __restrict__ cnt,
                            int ne) {
  const int i = blockIdx.x * blockDim.x + threadIdx.x;
  if (i < ne) atomicAdd(&cnt[dst[i]], 1);
}
// Range allocation; also places the self-loop at slot start[i].
__global__ void alloc_ranges(const int* __restrict__ cnt, int* __restrict__ start,
                             int* __restrict__ cursor, int* __restrict__ total,
                             int* __restrict__ csr, int* __restrict__ csrd, int n) {
  const int i = blockIdx.x * blockDim.x + threadIdx.x;
  const int lane = threadIdx.x & 63;
  const int v = (i < n) ? cnt[i] : 0;
  int sc = v;
#pragma unroll
  for (int off = 1; off < 64; off <<= 1) {
    const int t = __shfl_up(sc, off);
    if (lane >= off) sc += t;
  }
  const int wtot = __shfl(sc, 63);
  int base = 0;
  if (lane == 63) base = atomicAdd(total, wtot);
  base = __shfl(base, 63);
  const int st = base + sc - v;
  if (i < n) {
    start[i] = st;
    cursor[i] = st + 1;
    csr[st] = i;   // self loop
    csrd[st] = i;
  }
}
__global__ void fill_edges(const int* __restrict__ src, const int* __restrict__ dst,
                           int* __restrict__ cursor, int* __restrict__ csr,
                           int* __restrict__ csrd, int ne) {
  const int i = blockIdx.x * blockDim.x + threadIdx.x;
  if (i < ne) {
    const int d = dst[i];
    const int p = atomicAdd(&cursor[d], 1);
    csr[p] = src[i];
    csrd[p] = d;
  }
}

// ---------------- edge-parallel leaky scores (CSR order) --------------
template <int NH>
__global__ void edge_scores(const int* __restrict__ csr_src,
                            const int* __restrict__ csr_dst,
                            const float* __restrict__ asrc,
                            const float* __restrict__ adst,
                            float* __restrict__ esc, int ne) {
  const int idx = blockIdx.x * blockDim.x + threadIdx.x;
  if (idx >= ne * NH) return;
  const int p = idx / NH;
  const int hh = idx - p * NH;
  const float e = asrc[csr_src[p] * NH + hh] + adst[csr_dst[p] * NH + hh];
  esc[idx] = (e > 0.f) ? e : kNegSlope * e;
}

// ---------------- GAT aggregate, layers 1-2 ---------------------------
// 2 waves per node, lane owns 4 contiguous channels (full float4 gathers).
__global__ void gat_agg4(const float* __restrict__ h, const float* __restrict__ esc,
                         const int* __restrict__ start, const int* __restrict__ cnt,
                         const int* __restrict__ csr_src,
                         const float* __restrict__ bias,
                         _Float16* __restrict__ outH, _Float16* __restrict__ outL,
                         int n_nodes) {
  const int gtid = blockIdx.x * blockDim.x + threadIdx.x;
  const int wid = gtid >> 6;
  const int node = wid >> 1;
  const int sub = wid & 1;
  const int lane = threadIdx.x & 63;
  if (node >= n_nodes) return;
  const int ch = sub * 256 + lane * 4;
  const int head = ch >> 7;
  const int s = start[node];
  const int c = cnt[node];
  float m = -1e30f;
  for (int i = 0; i < c; ++i) m = fmaxf(m, esc[(size_t)(s + i) * 4 + head]);
  float4 acc = make_float4(0.f, 0.f, 0.f, 0.f);
  float denom = 0.f;
  int src = csr_src[s];
  for (int i = 0; i < c; ++i) {
    const int nsrc = (i + 1 < c) ? csr_src[s + i + 1] : 0;
    const float e = esc[(size_t)(s + i) * 4 + head];
    const float wgt = expf(e - m);
    denom += wgt;
    const float4 v = *(const float4*)(h + (size_t)src * 512 + ch);
    acc.x = fmaf(wgt, v.x, acc.x);
    acc.y = fmaf(wgt, v.y, acc.y);
    acc.z = fmaf(wgt, v.z, acc.z);
    acc.w = fmaf(wgt, v.w, acc.w);
    src = nsrc;
  }
  const float inv = 1.f / (denom + 1e-16f);
  float res[4] = {acc.x, acc.y, acc.z, acc.w};
  half4 H, L;
#pragma unroll
  for (int j = 0; j < 4; ++j) {
    float v = res[j] * inv + bias[ch + j];
    v = (v > 0.f) ? v : expm1f(v);  // elu
    const _Float16 hv = (_Float16)v;
    H[j] = hv;
    L[j] = (_Float16)(v - (float)hv);
  }
  *(half4*)(outH + (size_t)node * 512 + ch) = H;
  *(half4*)(outL + (size_t)node * 512 + ch) = L;
}

// ---------------- GAT aggregate, layer 3 (H=1, fp32 out, no elu) ------
__global__ void gat_agg_l3(const float* __restrict__ h, const float* __restrict__ esc,
                           const int* __restrict__ start, const int* __restrict__ cnt,
                           const int* __restrict__ csr_src,
                           const float* __restrict__ bias,
                           float* __restrict__ out, int n_nodes) {
  const int gtid = blockIdx.x * blockDim.x + threadIdx.x;
  const int node = gtid >> 6;
  const int lane = threadIdx.x & 63;
  if (node >= n_nodes) return;
  const int s = start[node];
  const int c = cnt[node];
  float m = -1e30f;
  for (int i = 0; i < c; ++i) m = fmaxf(m, esc[s + i]);
  float2 acc = make_float2(0.f, 0.f);
  float denom = 0.f;
  int src = csr_src[s];
  for (int i = 0; i < c; ++i) {
    const int nsrc = (i + 1 < c) ? csr_src[s + i + 1] : 0;
    const float wgt = expf(esc[s + i] - m);
    denom += wgt;
    const float2 v = *(const float2*)(h + (size_t)src * 128 + lane * 2);
    acc.x = fmaf(wgt, v.x, acc.x);
    acc.y = fmaf(wgt, v.y, acc.y);
    src = nsrc;
  }
  const float inv = 1.f / (denom + 1e-16f);
  *(float2*)(out + (size_t)node * 128 + lane * 2) =
      make_float2(acc.x * inv + bias[lane * 2], acc.y * inv + bias[lane * 2 + 1]);
}

// ---------------- global max pool over sorted batch -------------------
__global__ void pool_max(const float* __restrict__ x, const int* __restrict__ batch,
                         float* __restrict__ emb, int n_nodes) {
  __shared__ int lohi[2];
  const int g = blockIdx.x;
  if (threadIdx.x == 0) {
    int lo = 0, hi = n_nodes;
    while (lo < hi) {
      const int mid = (lo + hi) >> 1;
      if (batch[mid] < g) lo = mid + 1; else hi = mid;
    }
    lohi[0] = lo;
    hi = n_nodes;
    while (lo < hi) {
      const int mid = (lo + hi) >> 1;
      if (batch[mid] < g + 1) lo = mid + 1; else hi = mid;
    }
    lohi[1] = lo;
  }
  __syncthreads();
  const int lo = lohi[0], hi = lohi[1];
  const int c = threadIdx.x;  // 128 channels
  float m = -1e30f;
  for (int nid = lo; nid < hi; ++nid) m = fmaxf(m, x[(size_t)nid * 128 + c]);
  emb[g * 128 + c] = (lo < hi) ? m : 0.f;
}

// ---------------- final MLP head --------------------------------------
__global__ void mlp_head(const float* __restrict__ e1, const float* __restrict__ e2,
                         const float* __restrict__ mw1, const float* __restrict__ mb1,
                         const float* __restrict__ mw2, const float* __restrict__ mb2,
                         float* __restrict__ out) {
  __shared__ float z[256];
  __shared__ float red[128];
  const int g = blockIdx.x;
  const int j = threadIdx.x;  // 128
  z[j] = e1[g * 128 + j];
  z[j + 128] = e2[g * 128 + j];
  __syncthreads();
  float acc = mb1[j];
  for (int k = 0; k < 256; ++k) acc = fmaf(z[k], mw1[k * 128 + j], acc);
  acc = fmaxf(acc, 0.f) * mw2[j];
  red[j] = acc;
  __syncthreads();
  for (int s = 64; s > 0; s >>= 1) {
    if (j < s) red[j] += red[j + s];
    __syncthreads();
  }
  if (j == 0) out[g] = red[0] + mb2[0];
}

// ---------------- launcher --------------------------------------------
extern "C" void kernel_launch(void* const* d_in, const int* in_sizes, int n_in,
                              void* d_out, int out_size, void* d_ws, size_t ws_size,
                              hipStream_t stream) {
  (void)in_sizes; (void)n_in; (void)out_size;
  const float* W1 = (const float*)d_in[6];
  const float* as1 = (const float*)d_in[7];
  const float* ad1 = (const float*)d_in[8];
  const float* b1 = (const float*)d_in[9];
  const float* W2 = (const float*)d_in[10];
  const float* as2 = (const float*)d_in[11];
  const float* ad2 = (const float*)d_in[12];
  const float* b2 = (const float*)d_in[13];
  const float* W3 = (const float*)d_in[14];
  const float* as3 = (const float*)d_in[15];
  const float* ad3 = (const float*)d_in[16];
  const float* b3 = (const float*)d_in[17];
  const float* mw1 = (const float*)d_in[18];
  const float* mb1 = (const float*)d_in[19];
  const float* mw2 = (const float*)d_in[20];
  const float* mb2 = (const float*)d_in[21];

  char* w = (char*)d_ws;
  size_t off = 0;
  auto take = [&](size_t bytes) -> void* {
    void* p = w + off;
    off += (bytes + 255) & ~(size_t)255;
    return p;
  };
  _Float16* R1h = (_Float16*)take((size_t)kN * 512 * 4);  // act hi/lo pair
  _Float16* R1l = R1h + (size_t)kN * 512;
  float* R1f = (float*)R1h;                               // layer-3 out alias
  float* R2 = (float*)take((size_t)kN * 512 * 4);         // h (GEMM out, fp32)
  float* asrc = (float*)take((size_t)kN * 4 * 4);
  float* adst = (float*)take((size_t)kN * 4 * 4);
  int* cnt    = (int*)take((size_t)kN * 4);
  int* start  = (int*)take((size_t)kN * 4);
  int* cursor = (int*)take((size_t)kN * 4);
  int* csr    = (int*)take((size_t)kE2 * 4);
  int* csrd   = (int*)take((size_t)kE2 * 4);
  float* esc  = (float*)take((size_t)kE2 * 4 * 4);
  int* total  = (int*)take(256);
  _Float16* Wth1 = (_Float16*)take((size_t)64 * 512 * 2);
  _Float16* Wtl1 = (_Float16*)take((size_t)64 * 512 * 2);
  _Float16* Wth2 = (_Float16*)take((size_t)512 * 512 * 2);
  _Float16* Wtl2 = (_Float16*)take((size_t)512 * 512 * 2);
  _Float16* Wth3 = (_Float16*)take((size_t)512 * 128 * 2);
  _Float16* Wtl3 = (_Float16*)take((size_t)512 * 128 * 2);
  float* emb = (float*)take((size_t)2 * kG * 128 * 4);
  if (off > ws_size) return;

  wt_split<<<(64 * 512 + 255) / 256, 256, 0, stream>>>(W1, Wth1, Wtl1, 64, 512);
  wt_split<<<(512 * 512 + 255) / 256, 256, 0, stream>>>(W2, Wth2, Wtl2, 512, 512);
  wt_split<<<(512 * 128 + 255) / 256, 256, 0, stream>>>(W3, Wth3, Wtl3, 512, 128);

  const int aggBlocks4 = (kN * 2 * 64) / 256;   // 2 waves per node
  const int aggBlocks1 = (kN * 64) / 256;       // 1 wave per node
  for (int enc = 0; enc < 2; ++enc) {
    const float* x = (const float*)d_in[enc * 3 + 0];
    const int* ei = (const int*)d_in[enc * 3 + 1];
    const int* batch = (const int*)d_in[enc * 3 + 2];
    const int* esrc = ei;
    const int* edst = ei + kE;
    float* embp = emb + (size_t)enc * kG * 128;

    // CSR by dst (self loop placed first in each segment)
    zero_int<<<1, 64, 0, stream>>>(total);
    init_counts<<<(kN + 255) / 256, 256, 0, stream>>>(cnt, kN);
    count_edges<<<(kE + 255) / 256, 256, 0, stream>>>(edst, cnt, kE);
    alloc_ranges<<<(kN + 255) / 256, 256, 0, stream>>>(cnt, start, cursor, total,
                                                       csr, csrd, kN);
    fill_edges<<<(kE + 255) / 256, 256, 0, stream>>>(esrc, edst, cursor, csr, csrd, kE);

    // layer-1 input split (dies after GEMM1; aliases R1 buffer)
    _Float16* A1h = R1h;
    _Float16* A1l = R1h + (size_t)kN * 64;
    split16<<<(kN * 64 + 255) / 256, 256, 0, stream>>>(x, A1h, A1l, kN * 64);

    // layer 1: [N,64] @ [64,512]
    zero_f2<<<(kN * 4 + 255) / 256, 256, 0, stream>>>(asrc, adst, kN * 4);
    gemm_f16x3<<<dim3((kN + 127) / 128, 4), 256, 0, stream>>>(
        A1h, A1l, Wth1, Wtl1, R2, as1, ad1, asrc, adst, kN, 512, 64, 4);
    edge_scores<4><<<(kE2 * 4 + 255) / 256, 256, 0, stream>>>(csr, csrd, asrc, adst,
                                                              esc, kE2);
    gat_agg4<<<aggBlocks4, 256, 0, stream>>>(R2, esc, start, cnt, csr, b1, R1h, R1l, kN);

    // layer 2: [N,512] @ [512,512]
    zero_f2<<<(kN * 4 + 255) / 256, 256, 0, stream>>>(asrc, adst, kN * 4);
    gemm_f16x3<<<dim3((kN + 127) / 128, 4), 256, 0, stream>>>(
        R1h, R1l, Wth2, Wtl2, R2, as2, ad2, asrc, adst, kN, 512, 512, 4);
    edge_scores<4><<<(kE2 * 4 + 255) / 256, 256, 0, stream>>>(csr, csrd, asrc, adst,
                                                              esc, kE2);
    gat_agg4<<<aggBlocks4, 256, 0, stream>>>(R2, esc, start, cnt, csr, b2, R1h, R1l, kN);

    // layer 3: [N,512] @ [512,128], H=1, no elu, fp32 out
    zero_f2<<<(kN + 255) / 256, 256, 0, stream>>>(asrc, adst, kN);
    gemm_f16x3<<<dim3((kN + 127) / 128, 1), 256, 0, stream>>>(
        R1h, R1l, Wth3, Wtl3, R2, as3, ad3, asrc, adst, kN, 128, 512, 1);
    edge_scores<1><<<(kE2 + 255) / 256, 256, 0, stream>>>(csr, csrd, asrc, adst,
                                                          esc, kE2);
    gat_agg_l3<<<aggBlocks1, 256, 0, stream>>>(R2, esc, start, cnt, csr, b3, R1f, kN);

    pool_max<<<kG, 128, 0, stream>>>(R1f, batch, embp, kN);
  }
  mlp_head<<<kG, 128, 0, stream>>>(emb, emb + (size_t)kG * 128, mw1, mb1, mw2, mb2,
                                   (float*)d_out);
}

// Round 4
// 1213.161 us; speedup vs baseline: 1.1238x; 1.1238x over previous
//
#include <hip/hip_runtime.h>
#include <cstdint>

namespace {
constexpr int kN = 50000;          // nodes
constexpr int kE = 200000;         // directed edges (pre self-loop)
constexpr int kE2 = kE + kN;       // with self loops
constexpr int kG = 256;            // graphs
constexpr float kNegSlope = 0.2f;
}

using half8   = __attribute__((ext_vector_type(8))) _Float16;
using half4   = __attribute__((ext_vector_type(4))) _Float16;
using floatx4 = __attribute__((ext_vector_type(4))) float;

__device__ __forceinline__ void gld_lds16(const void* g, void* l) {
  __builtin_amdgcn_global_load_lds(
      (const __attribute__((address_space(1))) unsigned int*)g,
      (__attribute__((address_space(3))) unsigned int*)l, 16, 0, 0);
}

// ---------------- f16x3 MFMA GEMM: C[M,N] = A[M,K] @ B[K,N] ----------
// A row-major hi/lo f16 [M,K]; B pre-transposed hi/lo f16 [N,K].
// 128x128 tile, BK=32, 256 threads = 4 waves (64x64 each).
// LDS slot s holds (row=(s>>6)*16+(s&15), kchunk=(s>>4)&3); fragment read
// g*1024 + lane*16 => conflict-free ds_read_b128, lane-contiguous staging.
__global__ __launch_bounds__(256) void gemm_f16x3(
    const _Float16* __restrict__ Ah, const _Float16* __restrict__ Al,
    const _Float16* __restrict__ Bh, const _Float16* __restrict__ Bl,
    float* __restrict__ C, int M, int N, int K) {
  __shared__ alignas(16) char smem[32768];
  char* sAh = smem;
  char* sAl = smem + 8192;
  char* sBh = smem + 16384;
  char* sBl = smem + 24576;
  const int t = threadIdx.x;
  const int w = t >> 6;
  const int l = t & 63;
  const int bm = blockIdx.x * 128;
  const int bn = blockIdx.y * 128;
  const int wm = (w & 1) * 64;
  const int wn = (w >> 1) * 64;
  const int quad = l >> 4;
  const int lrow = l & 15;

  floatx4 acc[4][4];
#pragma unroll
  for (int mi = 0; mi < 4; ++mi)
#pragma unroll
    for (int ni = 0; ni < 4; ++ni) acc[mi][ni] = (floatx4){0.f, 0.f, 0.f, 0.f};

  for (int k0 = 0; k0 < K; k0 += 32) {
#pragma unroll
    for (int j = 0; j < 2; ++j) {
      const int s = w * 128 + j * 64 + l;          // slot id 0..511
      const int row = ((s >> 6) << 4) + (s & 15);  // 0..127
      const int q = (s >> 4) & 3;
      int ga = bm + row;
      ga = (ga < M) ? ga : (M - 1);                // clamp: keep lanes active
      const size_t aofs = (size_t)ga * K + k0 + q * 8;
      const size_t bofs = (size_t)(bn + row) * K + k0 + q * 8;
      gld_lds16(Ah + aofs, sAh + s * 16);
      gld_lds16(Al + aofs, sAl + s * 16);
      gld_lds16(Bh + bofs, sBh + s * 16);
      gld_lds16(Bl + bofs, sBl + s * 16);
    }
    __syncthreads();
    half8 fah[4], fal[4], fbh[4], fbl[4];
#pragma unroll
    for (int mi = 0; mi < 4; ++mi) {
      const int g = (wm >> 4) + mi;
      fah[mi] = *(const half8*)(sAh + g * 1024 + l * 16);
      fal[mi] = *(const half8*)(sAl + g * 1024 + l * 16);
    }
#pragma unroll
    for (int ni = 0; ni < 4; ++ni) {
      const int g = (wn >> 4) + ni;
      fbh[ni] = *(const half8*)(sBh + g * 1024 + l * 16);
      fbl[ni] = *(const half8*)(sBl + g * 1024 + l * 16);
    }
#pragma unroll
    for (int mi = 0; mi < 4; ++mi)
#pragma unroll
      for (int ni = 0; ni < 4; ++ni) {
        acc[mi][ni] = __builtin_amdgcn_mfma_f32_16x16x32_f16(fal[mi], fbh[ni],
                                                             acc[mi][ni], 0, 0, 0);
        acc[mi][ni] = __builtin_amdgcn_mfma_f32_16x16x32_f16(fah[mi], fbl[ni],
                                                             acc[mi][ni], 0, 0, 0);
        acc[mi][ni] = __builtin_amdgcn_mfma_f32_16x16x32_f16(fah[mi], fbh[ni],
                                                             acc[mi][ni], 0, 0, 0);
      }
    __syncthreads();
  }
  // epilogue: C/D layout col=lane&15, row=quad*4+reg
#pragma unroll
  for (int mi = 0; mi < 4; ++mi) {
    const int rbase = bm + wm + mi * 16 + quad * 4;
#pragma unroll
    for (int r = 0; r < 4; ++r) {
      const int grow = rbase + r;
      if (grow < M) {
#pragma unroll
        for (int ni = 0; ni < 4; ++ni) {
          C[(size_t)grow * N + bn + wn + ni * 16 + lrow] = acc[mi][ni][r];
        }
      }
    }
  }
}

// ---------------- weight transpose + f16 split: W[K,N] -> Wt[N,K] -----
__global__ void wt_split(const float* __restrict__ W, _Float16* __restrict__ Th,
                         _Float16* __restrict__ Tl, int K, int N) {
  const int idx = blockIdx.x * blockDim.x + threadIdx.x;
  if (idx >= K * N) return;
  const int k = idx / N;
  const int n = idx - k * N;
  const float v = W[idx];
  const _Float16 h = (_Float16)v;
  Th[n * K + k] = h;
  Tl[n * K + k] = (_Float16)(v - (float)h);
}

// ---------------- row-major fp32 -> f16 hi/lo split -------------------
__global__ void split16(const float* __restrict__ X, _Float16* __restrict__ Xh,
                        _Float16* __restrict__ Xl, int total) {
  const int idx = blockIdx.x * blockDim.x + threadIdx.x;
  if (idx >= total) return;
  const float v = X[idx];
  const _Float16 h = (_Float16)v;
  Xh[idx] = h;
  Xl[idx] = (_Float16)(v - (float)h);
}

// ---------------- per-node attention dots -----------------------------
template <int VPL>
__global__ void node_alpha(const float* __restrict__ h,
                           const float* __restrict__ a_src,
                           const float* __restrict__ a_dst,
                           float* __restrict__ asrc,
                           float* __restrict__ adst, int n_nodes) {
  constexpr int WTOT = VPL * 64;
  constexpr int NH = WTOT / 128;
  constexpr int GRP = 128 / VPL;  // lanes per head
  const int gtid = blockIdx.x * blockDim.x + threadIdx.x;
  const int node = gtid >> 6;
  const int lane = threadIdx.x & 63;
  if (node >= n_nodes) return;
  const int head = (lane * VPL) >> 7;
  const float* hrow = h + (size_t)node * WTOT + lane * VPL;
  float s1 = 0.f, s2 = 0.f;
#pragma unroll
  for (int j = 0; j < VPL; ++j) {
    const float v = hrow[j];
    s1 = fmaf(v, a_src[lane * VPL + j], s1);
    s2 = fmaf(v, a_dst[lane * VPL + j], s2);
  }
#pragma unroll
  for (int off = 1; off < GRP; off <<= 1) {
    s1 += __shfl_xor(s1, off);
    s2 += __shfl_xor(s2, off);
  }
  if ((lane & (GRP - 1)) == 0) {
    asrc[node * NH + head] = s1;
    adst[node * NH + head] = s2;
  }
}

// ---------------- CSR (by dst) build ----------------------------------
__global__ void init_counts(int* __restrict__ cnt, int* __restrict__ total, int n) {
  const int i = blockIdx.x * blockDim.x + threadIdx.x;
  if (i < n) cnt[i] = 1;  // the self loop
  if (i == 0) *total = 0;
}
__global__ void count_edges(const int* __restrict__ dst, int* __restrict__ cnt,
                            int ne) {
  const int i = blockIdx.x * blockDim.x + threadIdx.x;
  if (i < ne) atomicAdd(&cnt[dst[i]], 1);
}
// Range allocation; also places the self-loop at slot start[i].
__global__ void alloc_ranges(const int* __restrict__ cnt, int* __restrict__ start,
                             int* __restrict__ cursor, int* __restrict__ total,
                             int* __restrict__ csr, int* __restrict__ csrd, int n) {
  const int i = blockIdx.x * blockDim.x + threadIdx.x;
  const int lane = threadIdx.x & 63;
  const int v = (i < n) ? cnt[i] : 0;
  int sc = v;
#pragma unroll
  for (int off = 1; off < 64; off <<= 1) {
    const int t = __shfl_up(sc, off);
    if (lane >= off) sc += t;
  }
  const int wtot = __shfl(sc, 63);
  int base = 0;
  if (lane == 63) base = atomicAdd(total, wtot);
  base = __shfl(base, 63);
  const int st = base + sc - v;
  if (i < n) {
    start[i] = st;
    cursor[i] = st + 1;
    csr[st] = i;   // self loop first
    csrd[st] = i;
  }
}
__global__ void fill_edges(const int* __restrict__ src, const int* __restrict__ dst,
                           int* __restrict__ cursor, int* __restrict__ csr,
                           int* __restrict__ csrd, int ne) {
  const int i = blockIdx.x * blockDim.x + threadIdx.x;
  if (i < ne) {
    const int d = dst[i];
    const int p = atomicAdd(&cursor[d], 1);
    csr[p] = src[i];
    csrd[p] = d;
  }
}

// ---------------- edge-parallel p = exp(leaky(e)) (CSR order) ---------
// Softmax is shift-invariant; scores are bounded (|e| << 88) so no max
// subtraction is needed — this removes a whole serial pass per node.
template <int NH>
__global__ void edge_scores(const int* __restrict__ csr_src,
                            const int* __restrict__ csr_dst,
                            const float* __restrict__ asrc,
                            const float* __restrict__ adst,
                            float* __restrict__ esc, int ne) {
  const int idx = blockIdx.x * blockDim.x + threadIdx.x;
  if (idx >= ne * NH) return;
  const int p = idx / NH;
  const int hh = idx - p * NH;
  const float e = asrc[csr_src[p] * NH + hh] + adst[csr_dst[p] * NH + hh];
  esc[idx] = expf((e > 0.f) ? e : kNegSlope * e);
}

// ---------------- GAT aggregate, layers 1-2 ---------------------------
// 2 waves per node, lane owns 4 contiguous channels (float4 gathers).
// Inner loop is pure load+fma (exp precomputed), unrolled x2.
__global__ void gat_agg4(const float* __restrict__ h, const float* __restrict__ esc,
                         const int* __restrict__ start, const int* __restrict__ cnt,
                         const int* __restrict__ csr_src,
                         const float* __restrict__ bias,
                         _Float16* __restrict__ outH, _Float16* __restrict__ outL,
                         int n_nodes) {
  const int gtid = blockIdx.x * blockDim.x + threadIdx.x;
  const int wid = gtid >> 6;
  const int node = wid >> 1;
  const int sub = wid & 1;
  const int lane = threadIdx.x & 63;
  if (node >= n_nodes) return;
  const int ch = sub * 256 + lane * 4;
  const int head = ch >> 7;
  const int s = start[node];
  const int c = cnt[node];
  float4 a0 = make_float4(0.f, 0.f, 0.f, 0.f);
  float4 a1 = make_float4(0.f, 0.f, 0.f, 0.f);
  float d0 = 0.f, d1 = 0.f;
  int i = 0;
  for (; i + 2 <= c; i += 2) {
    const float w0 = esc[(size_t)(s + i) * 4 + head];
    const float w1 = esc[(size_t)(s + i + 1) * 4 + head];
    const int s0 = csr_src[s + i];
    const int s1 = csr_src[s + i + 1];
    const float4 v0 = *(const float4*)(h + (size_t)s0 * 512 + ch);
    const float4 v1 = *(const float4*)(h + (size_t)s1 * 512 + ch);
    d0 += w0;
    d1 += w1;
    a0.x = fmaf(w0, v0.x, a0.x); a1.x = fmaf(w1, v1.x, a1.x);
    a0.y = fmaf(w0, v0.y, a0.y); a1.y = fmaf(w1, v1.y, a1.y);
    a0.z = fmaf(w0, v0.z, a0.z); a1.z = fmaf(w1, v1.z, a1.z);
    a0.w = fmaf(w0, v0.w, a0.w); a1.w = fmaf(w1, v1.w, a1.w);
  }
  if (i < c) {
    const float w0 = esc[(size_t)(s + i) * 4 + head];
    const int s0 = csr_src[s + i];
    const float4 v0 = *(const float4*)(h + (size_t)s0 * 512 + ch);
    d0 += w0;
    a0.x = fmaf(w0, v0.x, a0.x);
    a0.y = fmaf(w0, v0.y, a0.y);
    a0.z = fmaf(w0, v0.z, a0.z);
    a0.w = fmaf(w0, v0.w, a0.w);
  }
  const float inv = 1.f / (d0 + d1 + 1e-16f);
  float res[4] = {a0.x + a1.x, a0.y + a1.y, a0.z + a1.z, a0.w + a1.w};
  half4 H, L;
#pragma unroll
  for (int j = 0; j < 4; ++j) {
    float v = res[j] * inv + bias[ch + j];
    v = (v > 0.f) ? v : expm1f(v);  // elu
    const _Float16 hv = (_Float16)v;
    H[j] = hv;
    L[j] = (_Float16)(v - (float)hv);
  }
  *(half4*)(outH + (size_t)node * 512 + ch) = H;
  *(half4*)(outL + (size_t)node * 512 + ch) = L;
}

// ---------------- GAT aggregate, layer 3 (H=1, fp32 out, no elu) ------
__global__ void gat_agg_l3(const float* __restrict__ h, const float* __restrict__ esc,
                           const int* __restrict__ start, const int* __restrict__ cnt,
                           const int* __restrict__ csr_src,
                           const float* __restrict__ bias,
                           float* __restrict__ out, int n_nodes) {
  const int gtid = blockIdx.x * blockDim.x + threadIdx.x;
  const int node = gtid >> 6;
  const int lane = threadIdx.x & 63;
  if (node >= n_nodes) return;
  const int s = start[node];
  const int c = cnt[node];
  float2 a0 = make_float2(0.f, 0.f);
  float2 a1 = make_float2(0.f, 0.f);
  float d0 = 0.f, d1 = 0.f;
  int i = 0;
  for (; i + 2 <= c; i += 2) {
    const float w0 = esc[s + i];
    const float w1 = esc[s + i + 1];
    const int s0 = csr_src[s + i];
    const int s1 = csr_src[s + i + 1];
    const float2 v0 = *(const float2*)(h + (size_t)s0 * 128 + lane * 2);
    const float2 v1 = *(const float2*)(h + (size_t)s1 * 128 + lane * 2);
    d0 += w0;
    d1 += w1;
    a0.x = fmaf(w0, v0.x, a0.x); a1.x = fmaf(w1, v1.x, a1.x);
    a0.y = fmaf(w0, v0.y, a0.y); a1.y = fmaf(w1, v1.y, a1.y);
  }
  if (i < c) {
    const float w0 = esc[s + i];
    const int s0 = csr_src[s + i];
    const float2 v0 = *(const float2*)(h + (size_t)s0 * 128 + lane * 2);
    d0 += w0;
    a0.x = fmaf(w0, v0.x, a0.x);
    a0.y = fmaf(w0, v0.y, a0.y);
  }
  const float inv = 1.f / (d0 + d1 + 1e-16f);
  *(float2*)(out + (size_t)node * 128 + lane * 2) =
      make_float2((a0.x + a1.x) * inv + bias[lane * 2],
                  (a0.y + a1.y) * inv + bias[lane * 2 + 1]);
}

// ---------------- global max pool over sorted batch -------------------
__global__ void pool_max(const float* __restrict__ x, const int* __restrict__ batch,
                         float* __restrict__ emb, int n_nodes) {
  __shared__ int lohi[2];
  const int g = blockIdx.x;
  if (threadIdx.x == 0) {
    int lo = 0, hi = n_nodes;
    while (lo < hi) {
      const int mid = (lo + hi) >> 1;
      if (batch[mid] < g) lo = mid + 1; else hi = mid;
    }
    lohi[0] = lo;
    hi = n_nodes;
    while (lo < hi) {
      const int mid = (lo + hi) >> 1;
      if (batch[mid] < g + 1) lo = mid + 1; else hi = mid;
    }
    lohi[1] = lo;
  }
  __syncthreads();
  const int lo = lohi[0], hi = lohi[1];
  const int c = threadIdx.x;  // 128 channels
  float m = -1e30f;
  for (int nid = lo; nid < hi; ++nid) m = fmaxf(m, x[(size_t)nid * 128 + c]);
  emb[g * 128 + c] = (lo < hi) ? m : 0.f;
}

// ---------------- final MLP head --------------------------------------
__global__ void mlp_head(const float* __restrict__ e1, const float* __restrict__ e2,
                         const float* __restrict__ mw1, const float* __restrict__ mb1,
                         const float* __restrict__ mw2, const float* __restrict__ mb2,
                         float* __restrict__ out) {
  __shared__ float z[256];
  __shared__ float red[128];
  const int g = blockIdx.x;
  const int j = threadIdx.x;  // 128
  z[j] = e1[g * 128 + j];
  z[j + 128] = e2[g * 128 + j];
  __syncthreads();
  float acc = mb1[j];
  for (int k = 0; k < 256; ++k) acc = fmaf(z[k], mw1[k * 128 + j], acc);
  acc = fmaxf(acc, 0.f) * mw2[j];
  red[j] = acc;
  __syncthreads();
  for (int s = 64; s > 0; s >>= 1) {
    if (j < s) red[j] += red[j + s];
    __syncthreads();
  }
  if (j == 0) out[g] = red[0] + mb2[0];
}

// ---------------- launcher --------------------------------------------
extern "C" void kernel_launch(void* const* d_in, const int* in_sizes, int n_in,
                              void* d_out, int out_size, void* d_ws, size_t ws_size,
                              hipStream_t stream) {
  (void)in_sizes; (void)n_in; (void)out_size;
  const float* W1 = (const float*)d_in[6];
  const float* as1 = (const float*)d_in[7];
  const float* ad1 = (const float*)d_in[8];
  const float* b1 = (const float*)d_in[9];
  const float* W2 = (const float*)d_in[10];
  const float* as2 = (const float*)d_in[11];
  const float* ad2 = (const float*)d_in[12];
  const float* b2 = (const float*)d_in[13];
  const float* W3 = (const float*)d_in[14];
  const float* as3 = (const float*)d_in[15];
  const float* ad3 = (const float*)d_in[16];
  const float* b3 = (const float*)d_in[17];
  const float* mw1 = (const float*)d_in[18];
  const float* mb1 = (const float*)d_in[19];
  const float* mw2 = (const float*)d_in[20];
  const float* mb2 = (const float*)d_in[21];

  char* w = (char*)d_ws;
  size_t off = 0;
  auto take = [&](size_t bytes) -> void* {
    void* p = w + off;
    off += (bytes + 255) & ~(size_t)255;
    return p;
  };
  _Float16* R1h = (_Float16*)take((size_t)kN * 512 * 4);  // act hi/lo pair
  _Float16* R1l = R1h + (size_t)kN * 512;
  float* R1f = (float*)R1h;                               // layer-3 out alias
  float* R2 = (float*)take((size_t)kN * 512 * 4);         // h (GEMM out, fp32)
  float* asrc = (float*)take((size_t)kN * 4 * 4);
  float* adst = (float*)take((size_t)kN * 4 * 4);
  int* cnt    = (int*)take((size_t)kN * 4);
  int* start  = (int*)take((size_t)kN * 4);
  int* cursor = (int*)take((size_t)kN * 4);
  int* csr    = (int*)take((size_t)kE2 * 4);
  int* csrd   = (int*)take((size_t)kE2 * 4);
  float* esc  = (float*)take((size_t)kE2 * 4 * 4);
  int* total  = (int*)take(256);
  _Float16* Wth1 = (_Float16*)take((size_t)64 * 512 * 2);
  _Float16* Wtl1 = (_Float16*)take((size_t)64 * 512 * 2);
  _Float16* Wth2 = (_Float16*)take((size_t)512 * 512 * 2);
  _Float16* Wtl2 = (_Float16*)take((size_t)512 * 512 * 2);
  _Float16* Wth3 = (_Float16*)take((size_t)512 * 128 * 2);
  _Float16* Wtl3 = (_Float16*)take((size_t)512 * 128 * 2);
  float* emb = (float*)take((size_t)2 * kG * 128 * 4);
  if (off > ws_size) return;

  wt_split<<<(64 * 512 + 255) / 256, 256, 0, stream>>>(W1, Wth1, Wtl1, 64, 512);
  wt_split<<<(512 * 512 + 255) / 256, 256, 0, stream>>>(W2, Wth2, Wtl2, 512, 512);
  wt_split<<<(512 * 128 + 255) / 256, 256, 0, stream>>>(W3, Wth3, Wtl3, 512, 128);

  const int aggBlocks4 = (kN * 2 * 64) / 256;   // 2 waves per node
  const int aggBlocks1 = (kN * 64) / 256;       // 1 wave per node
  for (int enc = 0; enc < 2; ++enc) {
    const float* x = (const float*)d_in[enc * 3 + 0];
    const int* ei = (const int*)d_in[enc * 3 + 1];
    const int* batch = (const int*)d_in[enc * 3 + 2];
    const int* esrc = ei;
    const int* edst = ei + kE;
    float* embp = emb + (size_t)enc * kG * 128;

    // CSR by dst (self loop placed first in each segment)
    init_counts<<<(kN + 255) / 256, 256, 0, stream>>>(cnt, total, kN);
    count_edges<<<(kE + 255) / 256, 256, 0, stream>>>(edst, cnt, kE);
    alloc_ranges<<<(kN + 255) / 256, 256, 0, stream>>>(cnt, start, cursor, total,
                                                       csr, csrd, kN);
    fill_edges<<<(kE + 255) / 256, 256, 0, stream>>>(esrc, edst, cursor, csr, csrd, kE);

    // layer-1 input split (dies after GEMM1; aliases R1 buffer)
    _Float16* A1h = R1h;
    _Float16* A1l = R1h + (size_t)kN * 64;
    split16<<<(kN * 64 + 255) / 256, 256, 0, stream>>>(x, A1h, A1l, kN * 64);

    // layer 1: [N,64] @ [64,512]
    gemm_f16x3<<<dim3((kN + 127) / 128, 4), 256, 0, stream>>>(A1h, A1l, Wth1, Wtl1,
                                                              R2, kN, 512, 64);
    node_alpha<8><<<aggBlocks1, 256, 0, stream>>>(R2, as1, ad1, asrc, adst, kN);
    edge_scores<4><<<(kE2 * 4 + 255) / 256, 256, 0, stream>>>(csr, csrd, asrc, adst,
                                                              esc, kE2);
    gat_agg4<<<aggBlocks4, 256, 0, stream>>>(R2, esc, start, cnt, csr, b1, R1h, R1l, kN);

    // layer 2: [N,512] @ [512,512]
    gemm_f16x3<<<dim3((kN + 127) / 128, 4), 256, 0, stream>>>(R1h, R1l, Wth2, Wtl2,
                                                              R2, kN, 512, 512);
    node_alpha<8><<<aggBlocks1, 256, 0, stream>>>(R2, as2, ad2, asrc, adst, kN);
    edge_scores<4><<<(kE2 * 4 + 255) / 256, 256, 0, stream>>>(csr, csrd, asrc, adst,
                                                              esc, kE2);
    gat_agg4<<<aggBlocks4, 256, 0, stream>>>(R2, esc, start, cnt, csr, b2, R1h, R1l, kN);

    // layer 3: [N,512] @ [512,128], H=1, no elu, fp32 out
    gemm_f16x3<<<dim3((kN + 127) / 128, 1), 256, 0, stream>>>(R1h, R1l, Wth3, Wtl3,
                                                              R2, kN, 128, 512);
    node_alpha<2><<<aggBlocks1, 256, 0, stream>>>(R2, as3, ad3, asrc, adst, kN);
    edge_scores<1><<<(kE2 + 255) / 256, 256, 0, stream>>>(csr, csrd, asrc, adst,
                                                          esc, kE2);
    gat_agg_l3<<<aggBlocks1, 256, 0, stream>>>(R2, esc, start, cnt, csr, b3, R1f, kN);

    pool_max<<<kG, 128, 0, stream>>>(R1f, batch, embp, kN);
  }
  mlp_head<<<kG, 128, 0, stream>>>(emb, emb + (size_t)kG * 128, mw1, mb1, mw2, mb2,
                                   (float*)d_out);
}